// Round 1
// baseline (324.008 us; speedup 1.0000x reference)
//
#include <hip/hip_runtime.h>

// Problem constants (match reference)
#define B_  16
#define N_  65536
#define G_  64
#define M_  (N_ + G_)      // 65600 rois per batch (rois + appended gt)
#define R_  128            // ROIS_PER_IMAGE
#define FGP 32             // FG_PER_IMAGE
#define NB_ 8192           // buckets for rank selection over u_perm in [0,1)

// ---------------------------------------------------------------------------
// K1: per-roi IoU max/argmax vs 64 gts + class masks + counters + histogram
// ---------------------------------------------------------------------------
__global__ void iou_kernel(const float* __restrict__ all_rois,
                           const float* __restrict__ gt_boxes,
                           const float* __restrict__ u_perm,
                           float* __restrict__ max_ov,
                           int*   __restrict__ gt_assign,
                           int*   __restrict__ fg_cnt,
                           int*   __restrict__ bg_cnt,
                           int*   __restrict__ hist)
{
    __shared__ float gx1[G_], gy1[G_], gx2[G_], gy2[G_], garea[G_];
    __shared__ int   gzero[G_];
    const int b   = blockIdx.y;
    const int tid = threadIdx.x;
    if (tid < G_) {
        const float* g = gt_boxes + (b * G_ + tid) * 6;
        float x1 = g[0], y1 = g[1], x2 = g[2], y2 = g[3];
        float gw = x2 - x1 + 1.0f, gh = y2 - y1 + 1.0f;
        gx1[tid] = x1; gy1[tid] = y1; gx2[tid] = x2; gy2[tid] = y2;
        garea[tid] = gw * gh;
        gzero[tid] = (gw == 1.0f && gh == 1.0f) ? 1 : 0;
    }
    __syncthreads();

    const int i = blockIdx.x * blockDim.x + tid;
    if (i >= M_) return;

    float x1, y1, x2, y2;
    if (i < N_) {
        const float* p = all_rois + ((size_t)b * N_ + i) * 5;
        x1 = p[1]; y1 = p[2]; x2 = p[3]; y2 = p[4];
    } else {
        const float* p = gt_boxes + (b * G_ + (i - N_)) * 6;
        x1 = p[0]; y1 = p[1]; x2 = p[2]; y2 = p[3];
    }
    float aw = x2 - x1 + 1.0f, ah = y2 - y1 + 1.0f;
    float area_a = aw * ah;
    bool  a_zero = (aw == 1.0f && ah == 1.0f);

    float best = -1e30f;
    int   bi   = 0;
    for (int j = 0; j < G_; ++j) {
        float iw = fminf(x2, gx2[j]) - fmaxf(x1, gx1[j]) + 1.0f;
        iw = fmaxf(iw, 0.0f);
        float ih = fminf(y2, gy2[j]) - fmaxf(y1, gy1[j]) + 1.0f;
        ih = fmaxf(ih, 0.0f);
        float inter = iw * ih;
        float ov = inter / (area_a + garea[j] - inter);  // IEEE div (no fast-math)
        if (gzero[j]) ov = 0.0f;
        if (ov > best) { best = ov; bi = j; }            // first-max = jnp.argmax
    }
    if (a_zero) { best = -1.0f; bi = 0; }                // a_zero overrides gt_zero

    max_ov   [(size_t)b * M_ + i] = best;
    gt_assign[(size_t)b * M_ + i] = bi;

    bool fg = best >= 0.7f;
    bool bg = best < 0.3f;   // == ((mo<0.3)&(mo>=0)) | (mo<0) given mo in {-1}∪[0,1]
    if (fg) atomicAdd(&fg_cnt[b], 1);
    if (bg) atomicAdd(&bg_cnt[b], 1);
    int cls = fg ? 0 : (bg ? 1 : -1);
    if (cls >= 0) {
        float u = u_perm[(size_t)b * M_ + i];
        int bucket = (int)(u * (float)NB_);              // monotone in u
        bucket = min(max(bucket, 0), NB_ - 1);
        atomicAdd(&hist[(b * 2 + cls) * NB_ + bucket], 1);
    }
}

// ---------------------------------------------------------------------------
// K2: exclusive prefix sum of each (batch,class) histogram, in place
// ---------------------------------------------------------------------------
__global__ void scan_kernel(int* __restrict__ hist)
{
    __shared__ int s[NB_];
    __shared__ int tot[256];
    int* h = hist + blockIdx.x * NB_;
    const int t = threadIdx.x;           // 256 threads
    for (int k = t; k < NB_; k += 256) s[k] = h[k];
    __syncthreads();
    const int base = t * 32;
    int run = 0;
    for (int kk = 0; kk < 32; ++kk) { int v = s[base + kk]; s[base + kk] = run; run += v; }
    tot[t] = run;
    __syncthreads();
    if (t == 0) {
        int acc = 0;
        for (int q = 0; q < 256; ++q) { int v = tot[q]; tot[q] = acc; acc += v; }
    }
    __syncthreads();
    const int off = tot[t];
    for (int kk = 0; kk < 32; ++kk) h[base + kk] = s[base + kk] + off;
}

// ---------------------------------------------------------------------------
// K3: scatter element indices into bucket-grouped storage
// ---------------------------------------------------------------------------
__global__ void scatter_kernel(const float* __restrict__ u_perm,
                               const float* __restrict__ max_ov,
                               const int*  __restrict__ prefix,
                               int*        __restrict__ fill,
                               int*        __restrict__ buckets)
{
    const int b = blockIdx.y;
    const int i = blockIdx.x * blockDim.x + threadIdx.x;
    if (i >= M_) return;
    float mo = max_ov[(size_t)b * M_ + i];
    bool fg = mo >= 0.7f, bg = mo < 0.3f;
    int cls = fg ? 0 : (bg ? 1 : -1);
    if (cls < 0) return;
    float u = u_perm[(size_t)b * M_ + i];
    int bucket = min(max((int)(u * (float)NB_), 0), NB_ - 1);
    int hidx = (b * 2 + cls) * NB_ + bucket;
    int p = prefix[hidx] + atomicAdd(&fill[hidx], 1);
    buckets[(size_t)(b * 2 + cls) * M_ + p] = i;
}

// ---------------------------------------------------------------------------
// K4: per-(batch,pos) rank selection + gather outputs
// ---------------------------------------------------------------------------
__global__ void sample_kernel(const float* __restrict__ all_rois,
                              const float* __restrict__ gt_boxes,
                              const float* __restrict__ u_perm,
                              const float* __restrict__ u_fg,
                              const float* __restrict__ u_bg,
                              const int*  __restrict__ fg_cnt,
                              const int*  __restrict__ bg_cnt,
                              const int*  __restrict__ prefix,
                              const int*  __restrict__ fill,
                              const int*  __restrict__ buckets,
                              const int*  __restrict__ gt_assign,
                              float*      __restrict__ out)
{
    const int b   = blockIdx.x;
    const int pos = threadIdx.x;   // 128 threads
    const int fgn = fg_cnt[b];
    const int bgn = bg_cnt[b];
    const bool both    = (fgn > 0) && (bgn > 0);
    const bool only_fg = (fgn > 0) && (bgn == 0);
    const int fg_this  = both ? min(FGP, fgn) : (only_fg ? R_ : 0);
    const bool is_fg   = pos < fg_this;

    int cls, rank, cnum;
    if (is_fg) {
        cls = 0; cnum = fgn;
        if (only_fg) {
            float uf = u_fg[b * R_ + pos];
            int kk = (int)(uf * (float)fgn);               // trunc toward zero, as astype(int32)
            rank = min(max(kk, 0), max(fgn - 1, 0));
        } else {
            rank = pos;
        }
    } else {
        cls = 1; cnum = bgn;
        float ub = u_bg[b * R_ + pos];
        int kk = (int)(ub * (float)bgn);
        rank = min(max(kk, 0), max(bgn - 1, 0));
    }

    int keep = 0;  // bg_num==0 edge: argsort(all 2.0, stable)[0] == 0
    if (cnum > 0) {
        const int* pref = prefix + (b * 2 + cls) * NB_;
        const int* fl   = fill   + (b * 2 + cls) * NB_;
        // largest j with pref[j] <= rank  (never lands on an empty bucket)
        int lo = 0, hi = NB_ - 1;
        while (lo < hi) {
            int mid = (lo + hi + 1) >> 1;
            if (pref[mid] <= rank) lo = mid; else hi = mid - 1;
        }
        const int bucket = lo;
        const int r      = rank - pref[bucket];
        const int cnt    = fl[bucket];
        const int*   be  = buckets + (size_t)(b * 2 + cls) * M_ + pref[bucket];
        const float* up  = u_perm + (size_t)b * M_;
        // r-th smallest by (u, idx): stable-argsort semantics, atomic-order independent
        for (int t2 = 0; t2 < cnt; ++t2) {
            int it = be[t2]; float ut = up[it];
            int rk = 0;
            for (int s2 = 0; s2 < cnt; ++s2) {
                if (s2 == t2) continue;
                int is2 = be[s2]; float us = up[is2];
                if (us < ut || (us == ut && is2 < it)) rk++;
            }
            if (rk == r) { keep = it; break; }
        }
    }

    // gather roi
    float ox1, oy1, ox2, oy2;
    if (keep < N_) {
        const float* p = all_rois + ((size_t)b * N_ + keep) * 5;
        ox1 = p[1]; oy1 = p[2]; ox2 = p[3]; oy2 = p[4];
    } else {
        const float* p = gt_boxes + (b * G_ + (keep - N_)) * 6;
        ox1 = p[0]; oy1 = p[1]; ox2 = p[2]; oy2 = p[3];
    }
    float* ro = out + ((size_t)b * R_ + pos) * 5;
    ro[0] = (float)b; ro[1] = ox1; ro[2] = oy1; ro[3] = ox2; ro[4] = oy2;

    float lab = 0.0f, tidv = -1.0f;
    if (is_fg) {
        int ga = gt_assign[(size_t)b * M_ + keep];
        lab  = gt_boxes[(b * G_ + ga) * 6 + 4];
        tidv = gt_boxes[(b * G_ + ga) * 6 + 5];
    }
    float* olab = out + (size_t)B_ * R_ * 5;
    float* otid = olab + (size_t)B_ * R_;
    olab[b * R_ + pos] = lab;
    otid[b * R_ + pos] = tidv;
}

// ---------------------------------------------------------------------------
extern "C" void kernel_launch(void* const* d_in, const int* in_sizes, int n_in,
                              void* d_out, int out_size, void* d_ws, size_t ws_size,
                              hipStream_t stream)
{
    const float* all_rois = (const float*)d_in[0];
    const float* gt_boxes = (const float*)d_in[1];
    const float* u_perm   = (const float*)d_in[2];
    const float* u_fg     = (const float*)d_in[3];
    const float* u_bg     = (const float*)d_in[4];
    float* out = (float*)d_out;

    // workspace layout (ints unless noted); total ~18.9 MB
    int* fg_cnt  = (int*)d_ws;                      // 16
    int* bg_cnt  = fg_cnt + 16;                     // 16
    int* hist    = bg_cnt + 16;                     // B*2*NB  (prefix after K2)
    int* fill    = hist + B_ * 2 * NB_;             // B*2*NB
    float* max_ov = (float*)(fill + B_ * 2 * NB_);  // B*M floats
    int* ga      = (int*)(max_ov + (size_t)B_ * M_);// B*M
    int* buckets = ga + (size_t)B_ * M_;            // B*2*M

    // zero counters + hist + fill (contiguous at the front)
    size_t zero_bytes = (size_t)(32 + 2 * B_ * 2 * NB_) * sizeof(int);
    hipMemsetAsync(d_ws, 0, zero_bytes, stream);

    dim3 grid1((M_ + 255) / 256, B_);
    iou_kernel<<<grid1, 256, 0, stream>>>(all_rois, gt_boxes, u_perm,
                                          max_ov, ga, fg_cnt, bg_cnt, hist);
    scan_kernel<<<B_ * 2, 256, 0, stream>>>(hist);
    scatter_kernel<<<grid1, 256, 0, stream>>>(u_perm, max_ov, hist, fill, buckets);
    sample_kernel<<<16, R_, 0, stream>>>(all_rois, gt_boxes, u_perm, u_fg, u_bg,
                                         fg_cnt, bg_cnt, hist, fill, buckets, ga, out);
}

// Round 2
// 318.766 us; speedup vs baseline: 1.0164x; 1.0164x over previous
//
#include <hip/hip_runtime.h>

// Problem constants (match reference)
#define B_  16
#define N_  65536
#define G_  64
#define M_  (N_ + G_)      // 65600 rois per batch (rois + appended gt)
#define R_  128            // ROIS_PER_IMAGE
#define FGP 32             // FG_PER_IMAGE
#define NB_ 8192           // buckets for rank selection over u_perm in [0,1)

// ---------------------------------------------------------------------------
// K0: precompute GT table, SoA [b][5][G]: x1,y1,x2,y2,area with gt_zero folded
//     in as poisoned coords (inter forced to 0 -> ov == +0.0 exactly).
// ---------------------------------------------------------------------------
__global__ void prep_kernel(const float* __restrict__ gt_boxes,
                            float* __restrict__ gtp)
{
    int t = blockIdx.x * blockDim.x + threadIdx.x;
    if (t >= B_ * G_) return;
    int b = t / G_, j = t % G_;
    const float* g = gt_boxes + t * 6;
    float x1 = g[0], y1 = g[1], x2 = g[2], y2 = g[3];
    float gw = x2 - x1 + 1.0f, gh = y2 - y1 + 1.0f;
    float area = gw * gh;
    bool gz = (gw == 1.0f) && (gh == 1.0f);
    float* o = gtp + b * 5 * G_;
    o[0 * G_ + j] = gz ?  3.0e8f : x1;
    o[1 * G_ + j] = gz ?  3.0e8f : y1;
    o[2 * G_ + j] = gz ? -3.0e8f : x2;
    o[3 * G_ + j] = gz ? -3.0e8f : y2;
    o[4 * G_ + j] = area;            // =1.0 for gz; denom stays positive
}

// ---------------------------------------------------------------------------
// K1: per-roi IoU max/argmax vs 64 gts + class masks + counters + histogram.
//     GT table read via block-uniform addresses -> scalar loads, no LDS,
//     unroll 16 for div-chain ILP.
// ---------------------------------------------------------------------------
__global__ void iou_kernel(const float* __restrict__ all_rois,
                           const float* __restrict__ gt_boxes,
                           const float* __restrict__ gtp,
                           const float* __restrict__ u_perm,
                           float* __restrict__ max_ov,
                           int*   __restrict__ gt_assign,
                           int*   __restrict__ fg_cnt,
                           int*   __restrict__ bg_cnt,
                           int*   __restrict__ hist)
{
    const int b = blockIdx.y;
    const int i = blockIdx.x * blockDim.x + threadIdx.x;
    if (i >= M_) return;

    float x1, y1, x2, y2;
    if (i < N_) {
        const float* p = all_rois + ((size_t)b * N_ + i) * 5;
        x1 = p[1]; y1 = p[2]; x2 = p[3]; y2 = p[4];
    } else {
        const float* p = gt_boxes + (b * G_ + (i - N_)) * 6;
        x1 = p[0]; y1 = p[1]; x2 = p[2]; y2 = p[3];
    }
    float aw = x2 - x1 + 1.0f, ah = y2 - y1 + 1.0f;
    float area_a = aw * ah;
    bool  a_zero = (aw == 1.0f) && (ah == 1.0f);

    const float* gp = gtp + b * 5 * G_;   // block-uniform base
    float best = -1e30f;
    int   bi   = 0;
    #pragma unroll 16
    for (int j = 0; j < G_; ++j) {
        float iw = fminf(x2, gp[2 * G_ + j]) - fmaxf(x1, gp[0 * G_ + j]) + 1.0f;
        float ih = fminf(y2, gp[3 * G_ + j]) - fmaxf(y1, gp[1 * G_ + j]) + 1.0f;
        iw = fmaxf(iw, 0.0f);
        ih = fmaxf(ih, 0.0f);
        float inter = iw * ih;
        float ov = inter / (area_a + gp[4 * G_ + j] - inter);  // IEEE div
        if (ov > best) { best = ov; bi = j; }                  // first-max
    }
    if (a_zero) { best = -1.0f; bi = 0; }                      // a_zero overrides

    max_ov   [(size_t)b * M_ + i] = best;
    gt_assign[(size_t)b * M_ + i] = bi;

    bool fg = best >= 0.7f;
    bool bg = best < 0.3f;   // == ((mo<0.3)&(mo>=0)) | (mo<0) given mo in {-1}∪[0,1]
    if (fg) atomicAdd(&fg_cnt[b], 1);
    if (bg) atomicAdd(&bg_cnt[b], 1);
    int cls = fg ? 0 : (bg ? 1 : -1);
    if (cls >= 0) {
        float u = u_perm[(size_t)b * M_ + i];
        int bucket = (int)(u * (float)NB_);              // monotone in u
        bucket = min(max(bucket, 0), NB_ - 1);
        atomicAdd(&hist[(b * 2 + cls) * NB_ + bucket], 1);
    }
}

// ---------------------------------------------------------------------------
// K2: exclusive prefix sum of each (batch,class) histogram, in place
// ---------------------------------------------------------------------------
__global__ void scan_kernel(int* __restrict__ hist)
{
    __shared__ int s[NB_];
    __shared__ int tot[256];
    int* h = hist + blockIdx.x * NB_;
    const int t = threadIdx.x;           // 256 threads
    for (int k = t; k < NB_; k += 256) s[k] = h[k];
    __syncthreads();
    const int base = t * 32;
    int run = 0;
    for (int kk = 0; kk < 32; ++kk) { int v = s[base + kk]; s[base + kk] = run; run += v; }
    tot[t] = run;
    __syncthreads();
    if (t == 0) {
        int acc = 0;
        for (int q = 0; q < 256; ++q) { int v = tot[q]; tot[q] = acc; acc += v; }
    }
    __syncthreads();
    const int off = tot[t];
    for (int kk = 0; kk < 32; ++kk) h[base + kk] = s[base + kk] + off;
}

// ---------------------------------------------------------------------------
// K3: scatter element indices into bucket-grouped storage
// ---------------------------------------------------------------------------
__global__ void scatter_kernel(const float* __restrict__ u_perm,
                               const float* __restrict__ max_ov,
                               const int*  __restrict__ prefix,
                               int*        __restrict__ fill,
                               int*        __restrict__ buckets)
{
    const int b = blockIdx.y;
    const int i = blockIdx.x * blockDim.x + threadIdx.x;
    if (i >= M_) return;
    float mo = max_ov[(size_t)b * M_ + i];
    bool fg = mo >= 0.7f, bg = mo < 0.3f;
    int cls = fg ? 0 : (bg ? 1 : -1);
    if (cls < 0) return;
    float u = u_perm[(size_t)b * M_ + i];
    int bucket = min(max((int)(u * (float)NB_), 0), NB_ - 1);
    int hidx = (b * 2 + cls) * NB_ + bucket;
    int p = prefix[hidx] + atomicAdd(&fill[hidx], 1);
    buckets[(size_t)(b * 2 + cls) * M_ + p] = i;
}

// ---------------------------------------------------------------------------
// K4: per-(batch,pos) rank selection + gather outputs
// ---------------------------------------------------------------------------
__global__ void sample_kernel(const float* __restrict__ all_rois,
                              const float* __restrict__ gt_boxes,
                              const float* __restrict__ u_perm,
                              const float* __restrict__ u_fg,
                              const float* __restrict__ u_bg,
                              const int*  __restrict__ fg_cnt,
                              const int*  __restrict__ bg_cnt,
                              const int*  __restrict__ prefix,
                              const int*  __restrict__ fill,
                              const int*  __restrict__ buckets,
                              const int*  __restrict__ gt_assign,
                              float*      __restrict__ out)
{
    const int b   = blockIdx.x;
    const int pos = threadIdx.x;   // 128 threads
    const int fgn = fg_cnt[b];
    const int bgn = bg_cnt[b];
    const bool both    = (fgn > 0) && (bgn > 0);
    const bool only_fg = (fgn > 0) && (bgn == 0);
    const int fg_this  = both ? min(FGP, fgn) : (only_fg ? R_ : 0);
    const bool is_fg   = pos < fg_this;

    int cls, rank, cnum;
    if (is_fg) {
        cls = 0; cnum = fgn;
        if (only_fg) {
            float uf = u_fg[b * R_ + pos];
            int kk = (int)(uf * (float)fgn);               // trunc toward zero
            rank = min(max(kk, 0), max(fgn - 1, 0));
        } else {
            rank = pos;
        }
    } else {
        cls = 1; cnum = bgn;
        float ub = u_bg[b * R_ + pos];
        int kk = (int)(ub * (float)bgn);
        rank = min(max(kk, 0), max(bgn - 1, 0));
    }

    int keep = 0;  // bg_num==0 edge: argsort(all 2.0, stable)[0] == 0
    if (cnum > 0) {
        const int* pref = prefix + (b * 2 + cls) * NB_;
        const int* fl   = fill   + (b * 2 + cls) * NB_;
        // largest j with pref[j] <= rank  (never lands on an empty bucket)
        int lo = 0, hi = NB_ - 1;
        while (lo < hi) {
            int mid = (lo + hi + 1) >> 1;
            if (pref[mid] <= rank) lo = mid; else hi = mid - 1;
        }
        const int bucket = lo;
        const int r      = rank - pref[bucket];
        const int cnt    = fl[bucket];
        const int*   be  = buckets + (size_t)(b * 2 + cls) * M_ + pref[bucket];
        const float* up  = u_perm + (size_t)b * M_;
        // r-th smallest by (u, idx): stable-argsort semantics, order independent
        for (int t2 = 0; t2 < cnt; ++t2) {
            int it = be[t2]; float ut = up[it];
            int rk = 0;
            for (int s2 = 0; s2 < cnt; ++s2) {
                if (s2 == t2) continue;
                int is2 = be[s2]; float us = up[is2];
                if (us < ut || (us == ut && is2 < it)) rk++;
            }
            if (rk == r) { keep = it; break; }
        }
    }

    // gather roi
    float ox1, oy1, ox2, oy2;
    if (keep < N_) {
        const float* p = all_rois + ((size_t)b * N_ + keep) * 5;
        ox1 = p[1]; oy1 = p[2]; ox2 = p[3]; oy2 = p[4];
    } else {
        const float* p = gt_boxes + (b * G_ + (keep - N_)) * 6;
        ox1 = p[0]; oy1 = p[1]; ox2 = p[2]; oy2 = p[3];
    }
    float* ro = out + ((size_t)b * R_ + pos) * 5;
    ro[0] = (float)b; ro[1] = ox1; ro[2] = oy1; ro[3] = ox2; ro[4] = oy2;

    float lab = 0.0f, tidv = -1.0f;
    if (is_fg) {
        int ga = gt_assign[(size_t)b * M_ + keep];
        lab  = gt_boxes[(b * G_ + ga) * 6 + 4];
        tidv = gt_boxes[(b * G_ + ga) * 6 + 5];
    }
    float* olab = out + (size_t)B_ * R_ * 5;
    float* otid = olab + (size_t)B_ * R_;
    olab[b * R_ + pos] = lab;
    otid[b * R_ + pos] = tidv;
}

// ---------------------------------------------------------------------------
extern "C" void kernel_launch(void* const* d_in, const int* in_sizes, int n_in,
                              void* d_out, int out_size, void* d_ws, size_t ws_size,
                              hipStream_t stream)
{
    const float* all_rois = (const float*)d_in[0];
    const float* gt_boxes = (const float*)d_in[1];
    const float* u_perm   = (const float*)d_in[2];
    const float* u_fg     = (const float*)d_in[3];
    const float* u_bg     = (const float*)d_in[4];
    float* out = (float*)d_out;

    // workspace layout (ints unless noted); total ~21 MB
    int* fg_cnt  = (int*)d_ws;                      // 16
    int* bg_cnt  = fg_cnt + 16;                     // 16
    int* hist    = bg_cnt + 16;                     // B*2*NB  (prefix after K2)
    int* fill    = hist + B_ * 2 * NB_;             // B*2*NB
    float* max_ov = (float*)(fill + B_ * 2 * NB_);  // B*M floats
    int* ga      = (int*)(max_ov + (size_t)B_ * M_);// B*M
    int* buckets = ga + (size_t)B_ * M_;            // B*2*M
    float* gtp   = (float*)(buckets + (size_t)B_ * 2 * M_);  // B*5*G floats

    // zero counters + hist + fill (contiguous at the front)
    size_t zero_bytes = (size_t)(32 + 2 * B_ * 2 * NB_) * sizeof(int);
    hipMemsetAsync(d_ws, 0, zero_bytes, stream);

    prep_kernel<<<(B_ * G_ + 255) / 256, 256, 0, stream>>>(gt_boxes, gtp);

    dim3 grid1((M_ + 255) / 256, B_);
    iou_kernel<<<grid1, 256, 0, stream>>>(all_rois, gt_boxes, gtp, u_perm,
                                          max_ov, ga, fg_cnt, bg_cnt, hist);
    scan_kernel<<<B_ * 2, 256, 0, stream>>>(hist);
    scatter_kernel<<<grid1, 256, 0, stream>>>(u_perm, max_ov, hist, fill, buckets);
    sample_kernel<<<16, R_, 0, stream>>>(all_rois, gt_boxes, u_perm, u_fg, u_bg,
                                         fg_cnt, bg_cnt, hist, fill, buckets, ga, out);
}